// Round 1
// baseline (1095.316 us; speedup 1.0000x reference)
//
#include <hip/hip_runtime.h>
#include <hip/hip_bf16.h>
#include <cstdint>
#include <cstddef>

#define B_ 64
#define S_ 4096
#define E_ 512
#define H_ 512
#define NEGV (-1.0e9f)

typedef short s8v __attribute__((ext_vector_type(8)));
typedef float f4v __attribute__((ext_vector_type(4)));

__device__ __forceinline__ unsigned short f2bf(float x) {
    unsigned u = __builtin_bit_cast(unsigned, x);
    u = u + 0x7FFFu + ((u >> 16) & 1u);          // RNE
    return (unsigned short)(u >> 16);
}
__device__ __forceinline__ float bf2f(unsigned short h) {
    unsigned u = ((unsigned)h) << 16;
    return __builtin_bit_cast(float, u);
}

// ---- W_enc -> transposed bf16 hi/lo: Wt[n][k] ----
__global__ void prep_w(const float* __restrict__ W_enc,
                       unsigned short* __restrict__ Wt_hi,
                       unsigned short* __restrict__ Wt_lo) {
    int n = blockIdx.x;
    for (int it = 0; it < 2; ++it) {
        int k = threadIdx.x + it * 256;
        float x = W_enc[(size_t)k * H_ + n];
        unsigned short h = f2bf(x);
        float r = x - bf2f(h);
        Wt_hi[(size_t)n * E_ + k] = h;
        Wt_lo[(size_t)n * E_ + k] = f2bf(r);
    }
}

// ---- decoded = dec @ W_dec (fp32, tiny) ----
__global__ void dec_proj(const float* __restrict__ dec,
                         const float* __restrict__ W_dec,
                         float* __restrict__ decoded) {
    __shared__ float sd[512];
    int b = blockIdx.x, tid = threadIdx.x;
    sd[tid]       = dec[b * 512 + tid];
    sd[tid + 256] = dec[b * 512 + tid + 256];
    __syncthreads();
    float a0 = 0.f, a1 = 0.f;
#pragma unroll 8
    for (int d = 0; d < 512; ++d) {
        float dv = sd[d];
        a0 += dv * W_dec[(size_t)d * 512 + tid];
        a1 += dv * W_dec[(size_t)d * 512 + tid + 256];
    }
    decoded[b * 512 + tid]       = a0;
    decoded[b * 512 + tid + 256] = a1;
}

// ---- fused: logits[b,s] += sum_h tanh((enc@W_enc)[s,h] + decoded[b,h]) * W_out[h]
// bf16x3 split MFMA GEMM, 128x128 tile, BK=32, 4 waves (2x2), 4x4 of 16x16x32 each
__global__ __launch_bounds__(256, 2)
void logits_gemm(const float* __restrict__ enc,
                 const unsigned short* __restrict__ Wt_hi,
                 const unsigned short* __restrict__ Wt_lo,
                 const float* __restrict__ decoded,
                 const float* __restrict__ W_out,
                 float* __restrict__ logits) {
    const int LDA = 40;  // 32 + 8 pad: frag reads land 2-way bank aliased (free)
    __shared__ __align__(16) unsigned short As_hi[128 * 40];
    __shared__ __align__(16) unsigned short As_lo[128 * 40];
    __shared__ __align__(16) unsigned short Bs_hi[128 * 40];
    __shared__ __align__(16) unsigned short Bs_lo[128 * 40];

    int bx = blockIdx.x;
    int ct = bx & 3, rt = bx >> 2;     // col tile fastest -> L3 reuse of A rows
    int r0 = rt * 128;
    int b  = r0 >> 12;                  // S=4096 rows per batch, 128 | 4096
    int sb = r0 & 4095;
    int nb0 = ct * 128;

    int tid  = threadIdx.x;
    int lane = tid & 63, wid = tid >> 6;
    int wr = wid >> 1, wc = wid & 1;
    int quad = lane >> 4, cl = lane & 15;

    f4v acc[4][4];
#pragma unroll
    for (int i = 0; i < 4; ++i)
#pragma unroll
        for (int j = 0; j < 4; ++j) acc[i][j] = (f4v)0.f;

    int a_k4 = tid & 7, a_m = tid >> 3;   // A staging: float4 per thread
    int b_k8 = tid & 3, b_n = tid >> 2;   // B staging: 8 bf16 per thread

    for (int k0 = 0; k0 < 512; k0 += 32) {
        __syncthreads();
        // stage A: 128 rows x 32 k, fp32 -> hi/lo bf16
#pragma unroll
        for (int mm = 0; mm < 4; ++mm) {
            int m = a_m + mm * 32;
            float4 v = *(const float4*)(enc + (size_t)(r0 + m) * E_ + k0 + a_k4 * 4);
            unsigned short h0 = f2bf(v.x), h1 = f2bf(v.y), h2 = f2bf(v.z), h3 = f2bf(v.w);
            unsigned short l0 = f2bf(v.x - bf2f(h0)), l1 = f2bf(v.y - bf2f(h1));
            unsigned short l2 = f2bf(v.z - bf2f(h2)), l3 = f2bf(v.w - bf2f(h3));
            uint2 ph, pl;
            ph.x = (unsigned)h0 | ((unsigned)h1 << 16); ph.y = (unsigned)h2 | ((unsigned)h3 << 16);
            pl.x = (unsigned)l0 | ((unsigned)l1 << 16); pl.y = (unsigned)l2 | ((unsigned)l3 << 16);
            *(uint2*)&As_hi[m * LDA + a_k4 * 4] = ph;
            *(uint2*)&As_lo[m * LDA + a_k4 * 4] = pl;
        }
        // stage B: 128 n x 32 k from pre-split Wt[n][k]
#pragma unroll
        for (int nn = 0; nn < 2; ++nn) {
            int n = b_n + nn * 64;
            *(uint4*)&Bs_hi[n * LDA + b_k8 * 8] =
                *(const uint4*)(Wt_hi + (size_t)(nb0 + n) * E_ + k0 + b_k8 * 8);
            *(uint4*)&Bs_lo[n * LDA + b_k8 * 8] =
                *(const uint4*)(Wt_lo + (size_t)(nb0 + n) * E_ + k0 + b_k8 * 8);
        }
        __syncthreads();

        s8v ah[4], al[4], bh[4], bl[4];
#pragma unroll
        for (int i = 0; i < 4; ++i) {
            int row = wr * 64 + i * 16 + cl;
            ah[i] = *(const s8v*)&As_hi[row * LDA + quad * 8];
            al[i] = *(const s8v*)&As_lo[row * LDA + quad * 8];
        }
#pragma unroll
        for (int j = 0; j < 4; ++j) {
            int col = wc * 64 + j * 16 + cl;
            bh[j] = *(const s8v*)&Bs_hi[col * LDA + quad * 8];
            bl[j] = *(const s8v*)&Bs_lo[col * LDA + quad * 8];
        }
        // 3 passes, dependent MFMAs 16 apart
#pragma unroll
        for (int i = 0; i < 4; ++i)
#pragma unroll
            for (int j = 0; j < 4; ++j)
                acc[i][j] = __builtin_amdgcn_mfma_f32_16x16x32_bf16(ah[i], bh[j], acc[i][j], 0, 0, 0);
#pragma unroll
        for (int i = 0; i < 4; ++i)
#pragma unroll
            for (int j = 0; j < 4; ++j)
                acc[i][j] = __builtin_amdgcn_mfma_f32_16x16x32_bf16(ah[i], bl[j], acc[i][j], 0, 0, 0);
#pragma unroll
        for (int i = 0; i < 4; ++i)
#pragma unroll
            for (int j = 0; j < 4; ++j)
                acc[i][j] = __builtin_amdgcn_mfma_f32_16x16x32_bf16(al[i], bh[j], acc[i][j], 0, 0, 0);
    }

    // epilogue: +decoded, tanh, *W_out, reduce over this tile's 128 h-cols
    float dcol[4], wcol[4];
#pragma unroll
    for (int j = 0; j < 4; ++j) {
        int h = nb0 + wc * 64 + j * 16 + cl;
        dcol[j] = decoded[b * 512 + h];
        wcol[j] = W_out[h];
    }
#pragma unroll
    for (int i = 0; i < 4; ++i) {
        float rs[4] = {0.f, 0.f, 0.f, 0.f};
#pragma unroll
        for (int j = 0; j < 4; ++j) {
#pragma unroll
            for (int r = 0; r < 4; ++r) {
                float x = acc[i][j][r] + dcol[j];
                float e = __expf(2.0f * x);          // inf-safe tanh
                float t = 1.0f - 2.0f / (e + 1.0f);
                rs[r] += t * wcol[j];
            }
        }
#pragma unroll
        for (int r = 0; r < 4; ++r) {
            rs[r] += __shfl_xor(rs[r], 1, 64);
            rs[r] += __shfl_xor(rs[r], 2, 64);
            rs[r] += __shfl_xor(rs[r], 4, 64);
            rs[r] += __shfl_xor(rs[r], 8, 64);
        }
        if (cl == 0) {
            int srow = sb + wr * 64 + i * 16 + quad * 4;
#pragma unroll
            for (int r = 0; r < 4; ++r)
                atomicAdd(&logits[(size_t)b * S_ + srow + r], rs[r]);
        }
    }
}

// ---- masked softmax per batch row ----
__global__ void softmax_k(const float* __restrict__ logits,
                          const int* __restrict__ mask,
                          float* __restrict__ probs) {
    __shared__ float red[4];
    int b = blockIdx.x, tid = threadIdx.x;
    int wid = tid >> 6, lane = tid & 63;
    float xs[16];
    float m = -INFINITY;
#pragma unroll
    for (int t = 0; t < 16; ++t) {
        int s = tid + t * 256;
        float x = logits[(size_t)b * S_ + s];
        if (mask[b * S_ + s] == 0) x = NEGV;
        xs[t] = x;
        m = fmaxf(m, x);
    }
#pragma unroll
    for (int off = 32; off >= 1; off >>= 1) m = fmaxf(m, __shfl_xor(m, off, 64));
    if (lane == 0) red[wid] = m;
    __syncthreads();
    m = fmaxf(fmaxf(red[0], red[1]), fmaxf(red[2], red[3]));
    float sum = 0.f;
#pragma unroll
    for (int t = 0; t < 16; ++t) { xs[t] = __expf(xs[t] - m); sum += xs[t]; }
#pragma unroll
    for (int off = 32; off >= 1; off >>= 1) sum += __shfl_xor(sum, off, 64);
    __syncthreads();
    if (lane == 0) red[wid] = sum;
    __syncthreads();
    sum = red[0] + red[1] + red[2] + red[3];
    float inv = 1.0f / sum;
#pragma unroll
    for (int t = 0; t < 16; ++t) probs[(size_t)b * S_ + tid + t * 256] = xs[t] * inv;
}

// ---- attn[b,e] = sum_s probs[b,s] * enc[b,s,e], skipping negligible rows ----
__global__ void attn_k(const float* __restrict__ enc,
                       const float* __restrict__ probs,
                       float* __restrict__ attn) {
    __shared__ float sp[512];
    int c = blockIdx.x, b = blockIdx.y, tid = threadIdx.x;
    int s0 = c * 512;
    sp[tid]       = probs[(size_t)b * S_ + s0 + tid];
    sp[tid + 256] = probs[(size_t)b * S_ + s0 + tid + 256];
    __syncthreads();
    int e0 = tid * 2;
    float a0 = 0.f, a1 = 0.f;
    for (int ss = 0; ss < 512; ++ss) {
        float p = sp[ss];
        if (p > 1e-8f) {   // wave-uniform skip; total skipped mass < 4e-5
            const float2 v = *(const float2*)(enc + (size_t)b * S_ * E_ + (size_t)(s0 + ss) * E_ + e0);
            a0 += p * v.x;
            a1 += p * v.y;
        }
    }
    atomicAdd(&attn[b * E_ + e0],     a0);
    atomicAdd(&attn[b * E_ + e0 + 1], a1);
}

extern "C" void kernel_launch(void* const* d_in, const int* in_sizes, int n_in,
                              void* d_out, int out_size, void* d_ws, size_t ws_size,
                              hipStream_t stream) {
    const float* enc   = (const float*)d_in[0];
    const float* dec   = (const float*)d_in[1];
    const int*   mask  = (const int*)d_in[2];
    const float* W_enc = (const float*)d_in[3];
    const float* W_dec = (const float*)d_in[4];
    const float* W_out = (const float*)d_in[5];

    char* ws = (char*)d_ws;
    unsigned short* Wt_hi   = (unsigned short*)(ws);             // 512 KB
    unsigned short* Wt_lo   = (unsigned short*)(ws + 524288);    // 512 KB
    float*          decoded = (float*)(ws + 1048576);            // 128 KB
    float*          logits  = (float*)(ws + 1179648);            // 1 MB

    float* attn  = (float*)d_out;               // [64,512]
    float* probs = (float*)d_out + B_ * E_;     // [64,4096]

    hipMemsetAsync(d_out, 0, (size_t)out_size * sizeof(float), stream);
    hipMemsetAsync(logits, 0, (size_t)B_ * S_ * sizeof(float), stream);

    prep_w<<<512, 256, 0, stream>>>(W_enc, Wt_hi, Wt_lo);
    dec_proj<<<B_, 256, 0, stream>>>(dec, W_dec, decoded);
    logits_gemm<<<(B_ * S_ / 128) * 4, 256, 0, stream>>>(enc, Wt_hi, Wt_lo, decoded, W_out, logits);
    softmax_k<<<B_, 256, 0, stream>>>(logits, mask, probs);
    attn_k<<<dim3(8, B_), 256, 0, stream>>>(enc, probs, attn);
}